// Round 10
// baseline (7124.116 us; speedup 1.0000x reference)
//
#include <hip/hip_runtime.h>
#include <math.h>

#define Bsz 128
#define Tsz 512
#define Esz 512
#define Hsz 1024
#define G4H 4096
#define Vsz 32000
#define NB  64           // lstm blocks (fat: 16 j-cols each)
#define BH  (Bsz * Hsz)

typedef __attribute__((ext_vector_type(8))) short short8;
typedef __attribute__((ext_vector_type(4))) short short4v;
typedef __attribute__((ext_vector_type(8))) __bf16 bf16x8;
typedef __attribute__((ext_vector_type(4))) float f32x4;
typedef __attribute__((ext_vector_type(4))) unsigned int uint4v;

__device__ inline unsigned short f2bf(float f) {
    unsigned u = __float_as_uint(f);
    u += 0x7fffu + ((u >> 16) & 1u);   // RTNE
    return (unsigned short)(u >> 16);
}
__device__ inline float bf2f(unsigned short s) {
    return __uint_as_float(((unsigned)s) << 16);
}
__device__ inline f32x4 mfma16(short8 a, short8 b, f32x4 c) {
    return __builtin_amdgcn_mfma_f32_16x16x32_bf16(
        __builtin_bit_cast(bf16x8, a), __builtin_bit_cast(bf16x8, b), c, 0, 0, 0);
}

// async 16B loads; early-clobber so dst never aliases addr regs
#define GLD16P(dst, p)  asm volatile("global_load_dwordx4 %0, %1, off"         : "=&v"(dst) : "v"(p))
#define GLD16C(dst, p)  asm volatile("global_load_dwordx4 %0, %1, off sc0 sc1" : "=&v"(dst) : "v"(p))

#define WAITVM(n)                                                          \
    do { asm volatile("s_waitcnt vmcnt(" #n ")" ::: "memory");             \
         __builtin_amdgcn_sched_barrier(0); } while (0)

// ---------------- prep kernels ----------------
__global__ void k_prep_emb(const float* __restrict__ emb, unsigned short* __restrict__ dst) {
    size_t i = (size_t)blockIdx.x * 256 + threadIdx.x;
    if (i < (size_t)Vsz * Esz) dst[i] = f2bf(i < Esz ? 0.f : emb[i]);  // row 0 = PAD -> 0
}

__global__ void k_prep_w(const float* __restrict__ wi, const float* __restrict__ wf,
                         const float* __restrict__ wg, const float* __restrict__ wo,
                         int ncols, unsigned short* __restrict__ dst) {
    size_t i = (size_t)blockIdx.x * 256 + threadIdx.x;
    size_t per = (size_t)Hsz * ncols;
    if (i < 4 * per) {
        int g = (int)(i / per);
        size_t rem = i - (size_t)g * per;
        const float* src = g == 0 ? wi : g == 1 ? wf : g == 2 ? wg : wo;
        dst[i] = f2bf(src[rem]);
    }
}

__global__ void k_prep_misc(const float* __restrict__ bi, const float* __restrict__ bff,
                            const float* __restrict__ bg, const float* __restrict__ bo,
                            float* __restrict__ b4, unsigned short* __restrict__ ghbuf,
                            float* __restrict__ cbuf, float* __restrict__ outh,
                            unsigned long long* __restrict__ bar) {
    int i = blockIdx.x * 256 + threadIdx.x;
    if (i < G4H) {
        const float* src = i < Hsz ? bi : i < 2 * Hsz ? bff : i < 3 * Hsz ? bg : bo;
        b4[i] = src[i & (Hsz - 1)];
    }
    if (i < 2 * BH) ghbuf[i] = 0;
    if (i < BH) { cbuf[i] = 0.f; outh[i] = 0.f; }
    if (i == 0) *bar = 0ull;
}

// ---------------- xp = emb[x] @ Wi^T + b  (layout [t'][bk64][b][jj16][gate4]) ----------------
__global__ __launch_bounds__(256, 2) void xp_gemm(
    const unsigned short* __restrict__ emb16, const unsigned short* __restrict__ Wi16,
    const float* __restrict__ b4, const int* __restrict__ x,
    unsigned short* __restrict__ xp, int t_base)
{
    const int tp = blockIdx.x;
    const int n0 = blockIdx.y * 128;
    const int tid = threadIdx.x;
    const int w = tid >> 6, l = tid & 63;
    const int wm = w >> 1, wn = w & 1;
    const int lr = l & 15, lk = l >> 4;

    const unsigned short* arow[4];
    #pragma unroll
    for (int mt = 0; mt < 4; ++mt) {
        int b = wm * 64 + mt * 16 + lr;
        int xv = x[b * Tsz + t_base + tp];
        arow[mt] = emb16 + (size_t)xv * Esz + lk * 8;
    }
    const unsigned short* brow[4];
    #pragma unroll
    for (int nt = 0; nt < 4; ++nt) {
        int n = n0 + wn * 64 + nt * 16 + lr;
        brow[nt] = Wi16 + (size_t)n * Esz + lk * 8;
    }
    f32x4 acc[4][4] = {};
    #pragma unroll 2
    for (int k0 = 0; k0 < Esz; k0 += 32) {
        short8 av[4], bv[4];
        #pragma unroll
        for (int mt = 0; mt < 4; ++mt) av[mt] = *(const short8*)(arow[mt] + k0);
        #pragma unroll
        for (int nt = 0; nt < 4; ++nt) bv[nt] = *(const short8*)(brow[nt] + k0);
        #pragma unroll
        for (int mt = 0; mt < 4; ++mt)
            #pragma unroll
            for (int nt = 0; nt < 4; ++nt)
                acc[mt][nt] = mfma16(av[mt], bv[nt], acc[mt][nt]);
    }
    #pragma unroll
    for (int nt = 0; nt < 4; ++nt) {
        int n = n0 + wn * 64 + nt * 16 + lr;
        float bias = b4[n];
        int g = n >> 10, j = n & 1023;
        int bk = j >> 4, jj = j & 15;
        #pragma unroll
        for (int mt = 0; mt < 4; ++mt) {
            #pragma unroll
            for (int r = 0; r < 4; ++r) {
                int b = wm * 64 + mt * 16 + lk * 4 + r;
                xp[((size_t)tp * NB + bk) * (Bsz * 64) + b * 64 + jj * 4 + g] =
                    f2bf(acc[mt][nt][r] + bias);
            }
        }
    }
}

// ---------------- fused recurrence ----------------
// 64 blocks x 4 waves (256 thr). Block owns 16 j-cols x 4 gates = 64 Wh rows in
// LDS (natural bank-balanced layout). Wave w: M=32 batch rows (2 A-tiles) x all
// 64 cols -> each LDS B-fragment feeds 2 MFMAs (B-read count halved vs R9).
// 3-chunk-deep load pipeline (24KB/wave in flight) covers MALL latency at
// 1 wave/SIMD. h: ghbuf[2][slab=64][b=128][16], MALL-coherent (sc0sc1 WT stores
// + sc0sc1 loads), flat u64 barrier (proven R5-R9).
__global__ __launch_bounds__(256, 1) void lstm_steps(
    const unsigned short* __restrict__ Wh16,
    const unsigned short* __restrict__ xp,    // [T'][NB][b][16][4] bf16 (gate-last)
    const int* __restrict__ lengths,
    unsigned short* __restrict__ ghbuf,       // [2][64][128][16] bf16 double buffer
    float* __restrict__ cbuf,
    float* __restrict__ outh,
    unsigned long long* __restrict__ bar,     // packed {gen:32, count:32}
    int t0, int nsteps)
{
    __shared__ unsigned short Whs[64][1032];   // 129 KB, natural layout
    __shared__ unsigned short xps[Bsz * 64];   // 16 KB: [b][jj][gate] current step
    __shared__ unsigned short hls[Bsz * 16];   // 4 KB: this block's h slab
    const int tid = threadIdx.x;
    const int blk = blockIdx.x;
    const int j0 = blk * 16;

    // stage Wh slice: local row n -> gate n>>4, col j0+(n&15); natural group order
    for (int idx = tid; idx < 64 * 128; idx += 256) {
        int n = idx >> 7, gq = idx & 127;
        int grow = (n >> 4) * Hsz + j0 + (n & 15);
        *(short8*)&Whs[n][gq << 3] =
            *(const short8*)(Wh16 + (size_t)grow * Hsz + gq * 8);
    }

    const int w = tid >> 6, l = tid & 63, lr = l & 15, lk = l >> 4;

    int lenr[2][4];
    float creg[2][4];
    #pragma unroll
    for (int m = 0; m < 2; ++m)
        #pragma unroll
        for (int r = 0; r < 4; ++r) {
            int b = 32 * w + 16 * m + 4 * lk + r;
            lenr[m][r] = lengths[b];
            creg[m][r] = cbuf[(size_t)b * Hsz + j0 + lr];
        }

    // prologue: stage xp slice for s=0 (16 KB = 256 thr x 64 B)
    {
        const short8* sp = (const short8*)(xp + (size_t)blk * (Bsz * 64));
        #pragma unroll
        for (int g = 0; g < 4; ++g)
            *(short8*)&xps[tid * 32 + g * 8] = sp[tid * 4 + g];
    }
    __syncthreads();

    // A-load lane base: row = 32w + lr (m0) / +16 (m1 = +256 shorts);
    // k0 = kc*128 + ks*32 + lk*8 -> slab = k0>>4, off = k0&15
    const int hb_off = (lk >> 1) * 2048 + (lk & 1) * 8 + (32 * w + lr) * 16;

#define ISSUE_CHUNK(buf, kc_) do {                                         \
        GLD16C(buf[0], hb + (kc_) * 16384 + 0);                            \
        GLD16C(buf[1], hb + (kc_) * 16384 + 4096);                         \
        GLD16C(buf[2], hb + (kc_) * 16384 + 8192);                         \
        GLD16C(buf[3], hb + (kc_) * 16384 + 12288);                        \
        GLD16C(buf[4], hb + (kc_) * 16384 + 256);                          \
        GLD16C(buf[5], hb + (kc_) * 16384 + 4096 + 256);                   \
        GLD16C(buf[6], hb + (kc_) * 16384 + 8192 + 256);                   \
        GLD16C(buf[7], hb + (kc_) * 16384 + 12288 + 256);                  \
    } while (0)

#define CONSUME(buf, kc_) do {                                             \
        _Pragma("unroll")                                                  \
        for (int ks_ = 0; ks_ < 4; ++ks_) {                                \
            short8 a0_ = __builtin_bit_cast(short8, buf[ks_]);             \
            short8 a1_ = __builtin_bit_cast(short8, buf[4 + ks_]);         \
            const int go_ = ((kc_) * 16 + ks_ * 4 + lk) << 3;              \
            _Pragma("unroll")                                              \
            for (int nt_ = 0; nt_ < 4; ++nt_) {                            \
                short8 bv_ = *(const short8*)&Whs[nt_ * 16 + lr][go_];     \
                acc0[nt_] = mfma16(a0_, bv_, acc0[nt_]);                   \
                acc1[nt_] = mfma16(a1_, bv_, acc1[nt_]);                   \
            }                                                              \
        }                                                                  \
    } while (0)

#define GATES(accX, mi_) do {                                              \
        _Pragma("unroll")                                                  \
        for (int r = 0; r < 4; ++r) {                                      \
            int b = 32 * w + 16 * (mi_) + 4 * lk + r;                      \
            short4v xg4 = *(const short4v*)&xps[b * 64 + lr * 4];          \
            float zi = accX[0][r] + bf2f((unsigned short)xg4[0]);          \
            float zf = accX[1][r] + bf2f((unsigned short)xg4[1]);          \
            float zg = accX[2][r] + bf2f((unsigned short)xg4[2]);          \
            float zo = accX[3][r] + bf2f((unsigned short)xg4[3]);          \
            float it = 1.f / (1.f + __expf(-zi));                          \
            float ft = 1.f / (1.f + __expf(-zf));                          \
            float gt = tanhf(zg);                                          \
            float ot = 1.f / (1.f + __expf(-zo));                          \
            float c = ft * creg[mi_][r] + it * gt;                         \
            creg[mi_][r] = c;                                              \
            float h = ot * tanhf(c);                                       \
            if (lenr[mi_][r] == t + 1) outh[(size_t)b * Hsz + j0 + lr] = h;\
            hls[b * 16 + lr] = f2bf(h);                                    \
        }                                                                  \
    } while (0)

    for (int s = 0; s < nsteps; ++s) {
        const int t = t0 + s;
        const unsigned short* hb = ghbuf + (size_t)(t & 1) * BH + hb_off;
        int sn = (s + 1 < nsteps) ? s + 1 : s;
        const unsigned short* xpn = xp + ((size_t)sn * NB + blk) * (Bsz * 64) + tid * 32;

        f32x4 acc0[4] = {}, acc1[4] = {};
        uint4v bufA[8], bufB[8], bufC[8], xr0, xr1, xr2, xr3;
        // 3-deep wait-then-consume pipeline; 8 loads/chunk
        ISSUE_CHUNK(bufA, 0);  ISSUE_CHUNK(bufB, 1);  ISSUE_CHUNK(bufC, 2);
        WAITVM(16);  CONSUME(bufA, 0);  ISSUE_CHUNK(bufA, 3);
        WAITVM(16);  CONSUME(bufB, 1);  ISSUE_CHUNK(bufB, 4);
        WAITVM(16);  CONSUME(bufC, 2);  ISSUE_CHUNK(bufC, 5);
        WAITVM(16);  CONSUME(bufA, 3);  ISSUE_CHUNK(bufA, 6);
        WAITVM(16);  CONSUME(bufB, 4);  ISSUE_CHUNK(bufB, 7);
        GLD16P(xr0, xpn); GLD16P(xr1, xpn + 8);
        GLD16P(xr2, xpn + 16); GLD16P(xr3, xpn + 24);
        WAITVM(20);  CONSUME(bufC, 5);
        WAITVM(12);  CONSUME(bufA, 6);
        WAITVM(4);   CONSUME(bufB, 7);          // xr may still be in flight

        // gates: lane owns (b = 32w+16m+4lk+r, j = j0+lr), all 4 gates in acc[nt][r]
        GATES(acc0, 0);
        GATES(acc1, 1);
        __syncthreads();   // hls complete (all waves); xps reads for step s done

        // coalesced h slab store: one contiguous 4KB burst, write-through to MALL
        unsigned short* ghn = ghbuf + (size_t)((t + 1) & 1) * BH;
        {
            short8 hv8 = *(const short8*)&hls[tid * 8];
            unsigned short* hd = ghn + (size_t)blk * 2048 + tid * 8;
            asm volatile("global_store_dwordx4 %0, %1, off sc0 sc1"
                         :: "v"(hd), "v"(__builtin_bit_cast(uint4v, hv8)) : "memory");
        }

        // drain stores + xr, then restage xps from prefetched regs
        WAITVM(0);
        *(short8*)&xps[tid * 32 + 0]  = __builtin_bit_cast(short8, xr0);
        *(short8*)&xps[tid * 32 + 8]  = __builtin_bit_cast(short8, xr1);
        *(short8*)&xps[tid * 32 + 16] = __builtin_bit_cast(short8, xr2);
        *(short8*)&xps[tid * 32 + 24] = __builtin_bit_cast(short8, xr3);

        // ---- grid barrier (single u64 {gen,count}, relaxed) ----
        if (tid == 0) {
            unsigned long long v = __hip_atomic_load(bar, __ATOMIC_RELAXED, __HIP_MEMORY_SCOPE_AGENT);
            unsigned gen = (unsigned)(v >> 32);
            unsigned long long old = __hip_atomic_fetch_add(bar, 1ull, __ATOMIC_RELAXED, __HIP_MEMORY_SCOPE_AGENT);
            if ((unsigned)old == NB - 1u) {
                __hip_atomic_fetch_add(bar, (1ull << 32) - (unsigned long long)NB,
                                       __ATOMIC_RELAXED, __HIP_MEMORY_SCOPE_AGENT);
            } else {
                unsigned long long cur;
                do {
                    __builtin_amdgcn_s_sleep(1);
                    cur = __hip_atomic_load(bar, __ATOMIC_RELAXED, __HIP_MEMORY_SCOPE_AGENT);
                } while ((unsigned)(cur >> 32) == gen);
            }
        }
        __syncthreads();
        __builtin_amdgcn_sched_barrier(0);   // keep next-step loads below the barrier
    }

    #pragma unroll
    for (int m = 0; m < 2; ++m)
        #pragma unroll
        for (int r = 0; r < 4; ++r) {
            int b = 32 * w + 16 * m + 4 * lk + r;
            cbuf[(size_t)b * Hsz + j0 + lr] = creg[m][r];
        }
#undef ISSUE_CHUNK
#undef CONSUME
#undef GATES
}

// ---------------- final fc ----------------
__global__ __launch_bounds__(64) void k_fc(const float* __restrict__ outh,
                                           const float* __restrict__ fc_w,
                                           const float* __restrict__ fc_b,
                                           float* __restrict__ out) {
    int b = blockIdx.x, l = threadIdx.x;
    float s = 0.f;
    for (int k = l; k < Hsz; k += 64) s += outh[(size_t)b * Hsz + k] * fc_w[k];
    #pragma unroll
    for (int o = 32; o > 0; o >>= 1) s += __shfl_down(s, o);
    if (l == 0) out[b] = s + fc_b[0];
}

extern "C" void kernel_launch(void* const* d_in, const int* in_sizes, int n_in,
                              void* d_out, int out_size, void* d_ws, size_t ws_size,
                              hipStream_t stream) {
    const int* x       = (const int*)d_in[0];
    const int* lengths = (const int*)d_in[1];
    const float* emb   = (const float*)d_in[2];
    const float* W_ii  = (const float*)d_in[3];
    const float* W_hi  = (const float*)d_in[4];
    const float* b_i   = (const float*)d_in[5];
    const float* W_if  = (const float*)d_in[6];
    const float* W_hf  = (const float*)d_in[7];
    const float* b_f   = (const float*)d_in[8];
    const float* W_ig  = (const float*)d_in[9];
    const float* W_hg  = (const float*)d_in[10];
    const float* b_g   = (const float*)d_in[11];
    const float* W_io  = (const float*)d_in[12];
    const float* W_ho  = (const float*)d_in[13];
    const float* b_o   = (const float*)d_in[14];
    const float* fc_w  = (const float*)d_in[15];
    const float* fc_b  = (const float*)d_in[16];
    float* out = (float*)d_out;

    char* ws = (char*)d_ws;
    size_t off = 0;
    auto take = [&](size_t bytes) { size_t o = off; off += (bytes + 255) & ~(size_t)255; return o; };
    unsigned long long* bar = (unsigned long long*)(ws + take(256));
    unsigned short* ghbuf = (unsigned short*)(ws + take((size_t)2 * BH * 2));
    float* cbuf           = (float*)(ws + take((size_t)BH * 4));
    float* outh           = (float*)(ws + take((size_t)BH * 4));
    float* b4             = (float*)(ws + take((size_t)G4H * 4));
    unsigned short* Wi16  = (unsigned short*)(ws + take((size_t)G4H * Esz * 2));
    unsigned short* Wh16  = (unsigned short*)(ws + take((size_t)G4H * Hsz * 2));
    unsigned short* emb16 = (unsigned short*)(ws + take((size_t)Vsz * Esz * 2));
    size_t fixed = off;

    int TC = 128;
    while (TC > 1 && fixed + (size_t)TC * Bsz * G4H * 2 > ws_size) TC >>= 1;
    unsigned short* xp = (unsigned short*)(ws + take((size_t)TC * Bsz * G4H * 2));

    k_prep_emb<<<(Vsz * Esz + 255) / 256, 256, 0, stream>>>(emb, emb16);
    k_prep_w<<<(4 * Hsz * Esz + 255) / 256, 256, 0, stream>>>(W_ii, W_if, W_ig, W_io, Esz, Wi16);
    k_prep_w<<<(4 * Hsz * Hsz + 255) / 256, 256, 0, stream>>>(W_hi, W_hf, W_hg, W_ho, Hsz, Wh16);
    k_prep_misc<<<(2 * BH + 255) / 256, 256, 0, stream>>>(b_i, b_f, b_g, b_o, b4, ghbuf, cbuf, outh, bar);

    for (int c = 0; c < Tsz / TC; ++c) {
        dim3 g(TC, 32);
        xp_gemm<<<g, 256, 0, stream>>>(emb16, Wi16, b4, x, xp, c * TC);
        lstm_steps<<<NB, 256, 0, stream>>>(Wh16, xp, lengths, ghbuf, cbuf, outh, bar, c * TC, TC);
    }
    k_fc<<<Bsz, 64, 0, stream>>>(outh, fc_w, fc_b, out);
}

// Round 11
// 4809.409 us; speedup vs baseline: 1.4813x; 1.4813x over previous
//
#include <hip/hip_runtime.h>
#include <math.h>

#define Bsz 128
#define Tsz 512
#define Esz 512
#define Hsz 1024
#define G4H 4096
#define Vsz 32000
#define NB  64           // lstm blocks (fat: 512 thr, 16 j-cols each)
#define BH  (Bsz * Hsz)
#define XPS 68           // padded xps row stride (shorts): 64 + 4 pad -> no 4-way bank conflict

typedef __attribute__((ext_vector_type(8))) short short8;
typedef __attribute__((ext_vector_type(4))) short short4v;
typedef __attribute__((ext_vector_type(8))) __bf16 bf16x8;
typedef __attribute__((ext_vector_type(4))) float f32x4;
typedef __attribute__((ext_vector_type(4))) unsigned int uint4v;

__device__ inline unsigned short f2bf(float f) {
    unsigned u = __float_as_uint(f);
    u += 0x7fffu + ((u >> 16) & 1u);   // RTNE
    return (unsigned short)(u >> 16);
}
__device__ inline float bf2f(unsigned short s) {
    return __uint_as_float(((unsigned)s) << 16);
}
__device__ inline f32x4 mfma16(short8 a, short8 b, f32x4 c) {
    return __builtin_amdgcn_mfma_f32_16x16x32_bf16(
        __builtin_bit_cast(bf16x8, a), __builtin_bit_cast(bf16x8, b), c, 0, 0, 0);
}

// async 16B loads; early-clobber so dst never aliases addr regs
#define GLD16P(dst, p)  asm volatile("global_load_dwordx4 %0, %1, off"         : "=&v"(dst) : "v"(p))
#define GLD16C(dst, p)  asm volatile("global_load_dwordx4 %0, %1, off sc0 sc1" : "=&v"(dst) : "v"(p))

#define WAITVM(n)                                                          \
    do { asm volatile("s_waitcnt vmcnt(" #n ")" ::: "memory");             \
         __builtin_amdgcn_sched_barrier(0); } while (0)

// MALL-coherent scalar flag ops (same primitives as the proven h exchange)
__device__ inline unsigned ld_flag(const unsigned* p) {
    unsigned r;
    asm volatile("global_load_dword %0, %1, off sc0 sc1\n\ts_waitcnt vmcnt(0)"
                 : "=&v"(r) : "v"(p) : "memory");
    return r;
}
__device__ inline void st_flag(unsigned* p, unsigned v) {
    asm volatile("global_store_dword %0, %1, off sc0 sc1" :: "v"(p), "v"(v) : "memory");
}

// ---------------- prep kernels ----------------
__global__ void k_prep_emb(const float* __restrict__ emb, unsigned short* __restrict__ dst) {
    size_t i = (size_t)blockIdx.x * 256 + threadIdx.x;
    if (i < (size_t)Vsz * Esz) dst[i] = f2bf(i < Esz ? 0.f : emb[i]);  // row 0 = PAD -> 0
}

__global__ void k_prep_w(const float* __restrict__ wi, const float* __restrict__ wf,
                         const float* __restrict__ wg, const float* __restrict__ wo,
                         int ncols, unsigned short* __restrict__ dst) {
    size_t i = (size_t)blockIdx.x * 256 + threadIdx.x;
    size_t per = (size_t)Hsz * ncols;
    if (i < 4 * per) {
        int g = (int)(i / per);
        size_t rem = i - (size_t)g * per;
        const float* src = g == 0 ? wi : g == 1 ? wf : g == 2 ? wg : wo;
        dst[i] = f2bf(src[rem]);
    }
}

__global__ void k_prep_misc(const float* __restrict__ bi, const float* __restrict__ bff,
                            const float* __restrict__ bg, const float* __restrict__ bo,
                            float* __restrict__ b4, unsigned short* __restrict__ ghbuf,
                            float* __restrict__ cbuf, float* __restrict__ outh,
                            unsigned* __restrict__ flags) {
    int i = blockIdx.x * 256 + threadIdx.x;
    if (i < G4H) {
        const float* src = i < Hsz ? bi : i < 2 * Hsz ? bff : i < 3 * Hsz ? bg : bo;
        b4[i] = src[i & (Hsz - 1)];
    }
    if (i < 2 * BH) ghbuf[i] = 0;
    if (i < BH) { cbuf[i] = 0.f; outh[i] = 0.f; }
    if (i < NB * 32) flags[i] = 0u;          // 64 flags, 128B-strided lines
}

// ---------------- xp = emb[x] @ Wi^T + b  (layout [t'][bk64][b][jj16][gate4]) ----------------
__global__ __launch_bounds__(256, 2) void xp_gemm(
    const unsigned short* __restrict__ emb16, const unsigned short* __restrict__ Wi16,
    const float* __restrict__ b4, const int* __restrict__ x,
    unsigned short* __restrict__ xp, int t_base)
{
    const int tp = blockIdx.x;
    const int n0 = blockIdx.y * 128;
    const int tid = threadIdx.x;
    const int w = tid >> 6, l = tid & 63;
    const int wm = w >> 1, wn = w & 1;
    const int lr = l & 15, lk = l >> 4;

    const unsigned short* arow[4];
    #pragma unroll
    for (int mt = 0; mt < 4; ++mt) {
        int b = wm * 64 + mt * 16 + lr;
        int xv = x[b * Tsz + t_base + tp];
        arow[mt] = emb16 + (size_t)xv * Esz + lk * 8;
    }
    const unsigned short* brow[4];
    #pragma unroll
    for (int nt = 0; nt < 4; ++nt) {
        int n = n0 + wn * 64 + nt * 16 + lr;
        brow[nt] = Wi16 + (size_t)n * Esz + lk * 8;
    }
    f32x4 acc[4][4] = {};
    #pragma unroll 2
    for (int k0 = 0; k0 < Esz; k0 += 32) {
        short8 av[4], bv[4];
        #pragma unroll
        for (int mt = 0; mt < 4; ++mt) av[mt] = *(const short8*)(arow[mt] + k0);
        #pragma unroll
        for (int nt = 0; nt < 4; ++nt) bv[nt] = *(const short8*)(brow[nt] + k0);
        #pragma unroll
        for (int mt = 0; mt < 4; ++mt)
            #pragma unroll
            for (int nt = 0; nt < 4; ++nt)
                acc[mt][nt] = mfma16(av[mt], bv[nt], acc[mt][nt]);
    }
    #pragma unroll
    for (int nt = 0; nt < 4; ++nt) {
        int n = n0 + wn * 64 + nt * 16 + lr;
        float bias = b4[n];
        int g = n >> 10, j = n & 1023;
        int bk = j >> 4, jj = j & 15;
        #pragma unroll
        for (int mt = 0; mt < 4; ++mt) {
            #pragma unroll
            for (int r = 0; r < 4; ++r) {
                int b = wm * 64 + mt * 16 + lk * 4 + r;
                xp[((size_t)tp * NB + bk) * (Bsz * 64) + b * 64 + jj * 4 + g] =
                    f2bf(acc[mt][nt][r] + bias);
            }
        }
    }
}

// ---------------- fused recurrence ----------------
// 64 blocks x 8 waves (R9-proven compute). Block owns 16 j-cols x 4 gates = 64
// Wh rows in LDS (natural bank-balanced layout). h: ghbuf[2][slab=64][b=128][16],
// MALL-coherent sc0sc1 exchange. Sync: decentralized per-block seqno flags
// (one 128B line each) -- post own flag after drained slab store, poll all 64.
__global__ __launch_bounds__(512, 1) void lstm_steps(
    const unsigned short* __restrict__ Wh16,
    const unsigned short* __restrict__ xp,    // [T'][NB][b][16][4] bf16 (gate-last)
    const int* __restrict__ lengths,
    unsigned short* __restrict__ ghbuf,       // [2][64][128][16] bf16 double buffer
    float* __restrict__ cbuf,
    float* __restrict__ outh,
    unsigned* __restrict__ flags,             // [64] seqno flags, stride 32 u32 (128B)
    int t0, int nsteps)
{
    __shared__ unsigned short Whs[64][1032];   // 129 KB, natural layout
    __shared__ unsigned short xps[Bsz * XPS];  // 17 KB: [b][jj][gate] padded stride 68
    __shared__ unsigned short hls[Bsz * 16];   // 4 KB: this block's h slab
    const int tid = threadIdx.x;
    const int blk = blockIdx.x;
    const int j0 = blk * 16;

    // stage Wh slice: local row n -> gate n>>4, col j0+(n&15); natural group order
    for (int idx = tid; idx < 64 * 128; idx += 512) {
        int n = idx >> 7, gq = idx & 127;
        int grow = (n >> 4) * Hsz + j0 + (n & 15);
        *(short8*)&Whs[n][gq << 3] =
            *(const short8*)(Wh16 + (size_t)grow * Hsz + gq * 8);
    }

    const int w = tid >> 6, l = tid & 63, lr = l & 15, lk = l >> 4;

    int lenr[4];
    float creg[4];
    #pragma unroll
    for (int r = 0; r < 4; ++r) {
        int b = 16 * w + 4 * lk + r;
        lenr[r] = lengths[b];
        creg[r] = cbuf[(size_t)b * Hsz + j0 + lr];
    }

    // prologue: stage xp slice for s=0 (thread -> b=tid>>2, quarter q=tid&3)
    {
        const short8* sp = (const short8*)(xp + (size_t)blk * (Bsz * 64));
        int xb = tid >> 2, xq = tid & 3;
        *(short8*)&xps[xb * XPS + xq * 16]     = sp[tid * 2];
        *(short8*)&xps[xb * XPS + xq * 16 + 8] = sp[tid * 2 + 1];
    }
    __syncthreads();

    // A-load lane base: k0 = kc*128 + ks*32 + lk*8 -> slab = k0>>4, off = k0&15
    const int hb_off = (lk >> 1) * 2048 + (lk & 1) * 8 + (16 * w + lr) * 16;

#define ISSUE_CHUNK(buf, kc_) do {                                         \
        GLD16C(buf[0], hb + (kc_) * 16384 + 0);                            \
        GLD16C(buf[1], hb + (kc_) * 16384 + 4096);                         \
        GLD16C(buf[2], hb + (kc_) * 16384 + 8192);                         \
        GLD16C(buf[3], hb + (kc_) * 16384 + 12288);                        \
    } while (0)

#define CONSUME(buf, kc_) do {                                             \
        _Pragma("unroll")                                                  \
        for (int ks_ = 0; ks_ < 4; ++ks_) {                                \
            short8 a_ = __builtin_bit_cast(short8, buf[ks_]);              \
            const int go_ = ((kc_) * 16 + ks_ * 4 + lk) << 3;              \
            _Pragma("unroll")                                              \
            for (int nt_ = 0; nt_ < 4; ++nt_) {                            \
                short8 bv_ = *(const short8*)&Whs[nt_ * 16 + lr][go_];     \
                acc[nt_] = mfma16(a_, bv_, acc[nt_]);                      \
            }                                                              \
        }                                                                  \
    } while (0)

    for (int s = 0; s < nsteps; ++s) {
        const int t = t0 + s;
        const unsigned short* hb = ghbuf + (size_t)(t & 1) * BH + hb_off;
        int sn = (s + 1 < nsteps) ? s + 1 : s;
        const unsigned short* xpn = xp + ((size_t)sn * NB + blk) * (Bsz * 64) + tid * 16;

        f32x4 acc[4] = {};
        uint4v A[4], Bb[4], xr0, xr1;
        // wait-then-consume pipeline, 4 loads/chunk, 2 chunks in flight (R9-proven)
        ISSUE_CHUNK(A, 0);  ISSUE_CHUNK(Bb, 1);
        WAITVM(4);  CONSUME(A, 0);   ISSUE_CHUNK(A, 2);
        WAITVM(4);  CONSUME(Bb, 1);  ISSUE_CHUNK(Bb, 3);
        WAITVM(4);  CONSUME(A, 2);   ISSUE_CHUNK(A, 4);
        WAITVM(4);  CONSUME(Bb, 3);  ISSUE_CHUNK(Bb, 5);
        WAITVM(4);  CONSUME(A, 4);   ISSUE_CHUNK(A, 6);
        WAITVM(4);  CONSUME(Bb, 5);  ISSUE_CHUNK(Bb, 7);
        GLD16P(xr0, xpn); GLD16P(xr1, xpn + 8);
        WAITVM(6);  CONSUME(A, 6);
        WAITVM(2);  CONSUME(Bb, 7);            // xr may still be in flight

        // gates: lane owns (b=16w+4lk+r, j=j0+lr); all 4 gates in acc[nt][r];
        // xp addend: one ds_read_b64 per r (padded stride -> conflict-free)
        #pragma unroll
        for (int r = 0; r < 4; ++r) {
            int b = 16 * w + 4 * lk + r;
            short4v xg4 = *(const short4v*)&xps[b * XPS + lr * 4];
            float zi = acc[0][r] + bf2f((unsigned short)xg4[0]);
            float zf = acc[1][r] + bf2f((unsigned short)xg4[1]);
            float zg = acc[2][r] + bf2f((unsigned short)xg4[2]);
            float zo = acc[3][r] + bf2f((unsigned short)xg4[3]);
            float it = 1.f / (1.f + __expf(-zi));
            float ft = 1.f / (1.f + __expf(-zf));
            float gt = tanhf(zg);
            float ot = 1.f / (1.f + __expf(-zo));
            float c = ft * creg[r] + it * gt;
            creg[r] = c;
            float h = ot * tanhf(c);
            if (lenr[r] == t + 1) outh[(size_t)b * Hsz + j0 + lr] = h;
            hls[b * 16 + lr] = f2bf(h);
        }
        __syncthreads();   // hls complete (all waves); xps reads for step s done

        // coalesced h slab store: one contiguous 4KB burst, write-through to MALL
        unsigned short* ghn = ghbuf + (size_t)((t + 1) & 1) * BH;
        if (tid < 256) {
            short8 hv8 = *(const short8*)&hls[tid * 8];
            unsigned short* hd = ghn + (size_t)blk * 2048 + tid * 8;
            asm volatile("global_store_dwordx4 %0, %1, off sc0 sc1"
                         :: "v"(hd), "v"(__builtin_bit_cast(uint4v, hv8)) : "memory");
        }

        // drain own stores + xr, then restage xps from prefetched regs
        WAITVM(0);
        {
            int xb = tid >> 2, xq = tid & 3;
            *(short8*)&xps[xb * XPS + xq * 16]     = __builtin_bit_cast(short8, xr0);
            *(short8*)&xps[xb * XPS + xq * 16 + 8] = __builtin_bit_cast(short8, xr1);
        }
        __syncthreads();   // ALL threads' slab stores ACKed at MALL; xps staged

        // ---- decentralized sync: post own seqno, poll all 64 ----
        if (tid == 0) st_flag(&flags[blk * 32], (unsigned)(t + 1));
        {
            const unsigned* fp = &flags[(tid & 63) * 32];
            while (ld_flag(fp) < (unsigned)(t + 1)) __builtin_amdgcn_s_sleep(1);
        }
        __syncthreads();
        __builtin_amdgcn_sched_barrier(0);   // keep next-step loads below the sync
    }

    #pragma unroll
    for (int r = 0; r < 4; ++r) {
        int b = 16 * w + 4 * lk + r;
        cbuf[(size_t)b * Hsz + j0 + lr] = creg[r];
    }
#undef ISSUE_CHUNK
#undef CONSUME
}

// ---------------- final fc ----------------
__global__ __launch_bounds__(64) void k_fc(const float* __restrict__ outh,
                                           const float* __restrict__ fc_w,
                                           const float* __restrict__ fc_b,
                                           float* __restrict__ out) {
    int b = blockIdx.x, l = threadIdx.x;
    float s = 0.f;
    for (int k = l; k < Hsz; k += 64) s += outh[(size_t)b * Hsz + k] * fc_w[k];
    #pragma unroll
    for (int o = 32; o > 0; o >>= 1) s += __shfl_down(s, o);
    if (l == 0) out[b] = s + fc_b[0];
}

extern "C" void kernel_launch(void* const* d_in, const int* in_sizes, int n_in,
                              void* d_out, int out_size, void* d_ws, size_t ws_size,
                              hipStream_t stream) {
    const int* x       = (const int*)d_in[0];
    const int* lengths = (const int*)d_in[1];
    const float* emb   = (const float*)d_in[2];
    const float* W_ii  = (const float*)d_in[3];
    const float* W_hi  = (const float*)d_in[4];
    const float* b_i   = (const float*)d_in[5];
    const float* W_if  = (const float*)d_in[6];
    const float* W_hf  = (const float*)d_in[7];
    const float* b_f   = (const float*)d_in[8];
    const float* W_ig  = (const float*)d_in[9];
    const float* W_hg  = (const float*)d_in[10];
    const float* b_g   = (const float*)d_in[11];
    const float* W_io  = (const float*)d_in[12];
    const float* W_ho  = (const float*)d_in[13];
    const float* b_o   = (const float*)d_in[14];
    const float* fc_w  = (const float*)d_in[15];
    const float* fc_b  = (const float*)d_in[16];
    float* out = (float*)d_out;

    char* ws = (char*)d_ws;
    size_t off = 0;
    auto take = [&](size_t bytes) { size_t o = off; off += (bytes + 255) & ~(size_t)255; return o; };
    unsigned* flags       = (unsigned*)(ws + take((size_t)NB * 128));
    unsigned short* ghbuf = (unsigned short*)(ws + take((size_t)2 * BH * 2));
    float* cbuf           = (float*)(ws + take((size_t)BH * 4));
    float* outh           = (float*)(ws + take((size_t)BH * 4));
    float* b4             = (float*)(ws + take((size_t)G4H * 4));
    unsigned short* Wi16  = (unsigned short*)(ws + take((size_t)G4H * Esz * 2));
    unsigned short* Wh16  = (unsigned short*)(ws + take((size_t)G4H * Hsz * 2));
    unsigned short* emb16 = (unsigned short*)(ws + take((size_t)Vsz * Esz * 2));
    size_t fixed = off;

    int TC = 128;
    while (TC > 1 && fixed + (size_t)TC * Bsz * G4H * 2 > ws_size) TC >>= 1;
    unsigned short* xp = (unsigned short*)(ws + take((size_t)TC * Bsz * G4H * 2));

    k_prep_emb<<<(Vsz * Esz + 255) / 256, 256, 0, stream>>>(emb, emb16);
    k_prep_w<<<(4 * Hsz * Esz + 255) / 256, 256, 0, stream>>>(W_ii, W_if, W_ig, W_io, Esz, Wi16);
    k_prep_w<<<(4 * Hsz * Hsz + 255) / 256, 256, 0, stream>>>(W_hi, W_hf, W_hg, W_ho, Hsz, Wh16);
    k_prep_misc<<<(2 * BH + 255) / 256, 256, 0, stream>>>(b_i, b_f, b_g, b_o, b4, ghbuf, cbuf, outh, flags);

    for (int c = 0; c < Tsz / TC; ++c) {
        dim3 g(TC, 32);
        xp_gemm<<<g, 256, 0, stream>>>(emb16, Wi16, b4, x, xp, c * TC);
        lstm_steps<<<NB, 512, 0, stream>>>(Wh16, xp, lengths, ghbuf, cbuf, outh, flags, c * TC, TC);
    }
    k_fc<<<Bsz, 64, 0, stream>>>(outh, fc_w, fc_b, out);
}